// Round 7
// baseline (361.941 us; speedup 1.0000x reference)
//
#include <hip/hip_runtime.h>
#include <cfloat>

// VQ quantizer — single kernel, no workspace.
// Per block (512 threads, 512 queries):
//   Phase A: thread t converts codebook row t -> fp16 (hi, lo*2048) MFMA
//            B-fragments in LDS (128 KiB) + cn[t]=||c_t||^2 (fp32 4-chain).
//   Scan   : barrier-free. Each wave: 64 queries (4 m-tiles) x 512 codes,
//            3-product split-fp16 MFMA (qh*ch + (ql'*ch + qh*cl')/2048).
//            Unpacked top-2 per query; approx error <~2.5e-4 << DELTA.
//   Refine : rows with gap <= DELTA (expected ~0.2/block) re-decided exactly
//            in fp64, 1 code/thread, deterministic (v, idx) ordering.
//   Output : gather rows into (reused) frag LDS, dense full-line stores.

#define DDIM  64
#define KCB   512
#define NQPB  512
#define DELTA 1.5e-3f
#define LO_SCALE 2048.0f

typedef _Float16 f16x8 __attribute__((ext_vector_type(8)));
typedef float    f32x4 __attribute__((ext_vector_type(4)));

__device__ __forceinline__ void split16(float f, _Float16& hi, _Float16& lo) {
    hi = (_Float16)f;                       // RTNE
    float r = f - (float)hi;                // exact
    lo = (_Float16)(r * LO_SCALE);          // scaled: stays normal-range
}

__global__ __launch_bounds__(512, 2) void vq(
    const float* __restrict__ ze, const float* __restrict__ cb,
    float* __restrict__ out)
{
    __shared__ __align__(16) char s_mem[131072];  // hi [0,64K) lo [64K,128K); later out-stage
    __shared__ float  s_cn[KCB];
    __shared__ int    s_bidx[NQPB];
    __shared__ int    s_flist[128];
    __shared__ int    s_nflag;
    __shared__ float  s_q[DDIM];
    __shared__ double s_rv[8];
    __shared__ int    s_ri[8];

    const int tid  = threadIdx.x;          // 0..511
    const int wave = tid >> 6;             // 0..7
    const int lane = tid & 63;
    const int quad = lane >> 4;            // 0..3
    const int l15  = lane & 15;
    const int qb   = blockIdx.x * NQPB;

    if (tid == 0) s_nflag = 0;

    // ---- A-fragments for this wave's 64 queries (issued early) ----
    union { f16x8 v; _Float16 h[8]; } qh[4][2], ql[4][2];
    #pragma unroll
    for (int m = 0; m < 4; ++m) {
        int row = qb + wave * 64 + m * 16 + l15;
        #pragma unroll
        for (int kb = 0; kb < 2; ++kb) {
            const float4* qs = (const float4*)(ze + (size_t)row * DDIM + kb * 32 + quad * 8);
            float4 a = qs[0], b = qs[1];
            float f[8] = {a.x,a.y,a.z,a.w,b.x,b.y,b.z,b.w};
            #pragma unroll
            for (int j = 0; j < 8; ++j) split16(f[j], qh[m][kb].h[j], ql[m][kb].h[j]);
        }
    }

    // ---- Phase A: codebook row `tid` -> LDS frags + cn ----
    {
        const float4* row = (const float4*)(cb + (size_t)tid * DDIM);
        float n0=0.f, n1=0.f, n2=0.f, n3=0.f;
        const int base = (tid >> 4) * 2;   // subkb base; +kb = (c8>>2)
        #pragma unroll
        for (int c8 = 0; c8 < 8; ++c8) {
            float4 a = row[c8*2], b = row[c8*2+1];
            n0=fmaf(a.x,a.x,n0); n1=fmaf(a.y,a.y,n1); n2=fmaf(a.z,a.z,n2); n3=fmaf(a.w,a.w,n3);
            n0=fmaf(b.x,b.x,n0); n1=fmaf(b.y,b.y,n1); n2=fmaf(b.z,b.z,n2); n3=fmaf(b.w,b.w,n3);
            union { _Float16 h[8]; float4 f4; } hi, lo;
            float f[8] = {a.x,a.y,a.z,a.w,b.x,b.y,b.z,b.w};
            #pragma unroll
            for (int j = 0; j < 8; ++j) split16(f[j], hi.h[j], lo.h[j]);
            // chunk layout consumed by scan: (SUB*2+kb)*64 + quad*16 + l15
            int chunk = (base + (c8 >> 2)) * 64 + (c8 & 3) * 16 + (tid & 15);
            *(float4*)(s_mem + (size_t)chunk * 16)         = hi.f4;
            *(float4*)(s_mem + 65536 + (size_t)chunk * 16) = lo.f4;
        }
        s_cn[tid] = (n0 + n1) + (n2 + n3);
    }
    __syncthreads();

    // ---- barrier-free scan: 32 subs x 24 MFMA ----
    float bb[4][4], ss[4][4]; int ii[4][4];
    #pragma unroll
    for (int m = 0; m < 4; ++m)
        #pragma unroll
        for (int r = 0; r < 4; ++r) { bb[m][r] = FLT_MAX; ss[m][r] = FLT_MAX; ii[m][r] = 0; }

    const f16x8* s_hi = (const f16x8*)s_mem;
    const f16x8* s_lo = (const f16x8*)(s_mem + 65536);

    #pragma unroll 2
    for (int SUB = 0; SUB < 32; ++SUB) {
        f16x8 bh0 = s_hi[(SUB*2+0)*64 + lane];
        f16x8 bl0 = s_lo[(SUB*2+0)*64 + lane];
        f16x8 bh1 = s_hi[(SUB*2+1)*64 + lane];
        f16x8 bl1 = s_lo[(SUB*2+1)*64 + lane];
        f32x4 ah[4], as_[4];
        #pragma unroll
        for (int m = 0; m < 4; ++m) {
            f32x4 z = {0.f,0.f,0.f,0.f};
            ah[m]  = __builtin_amdgcn_mfma_f32_16x16x32_f16(qh[m][0].v, bh0, z, 0,0,0);
            as_[m] = __builtin_amdgcn_mfma_f32_16x16x32_f16(ql[m][0].v, bh0, z, 0,0,0);
        }
        #pragma unroll
        for (int m = 0; m < 4; ++m) {
            as_[m] = __builtin_amdgcn_mfma_f32_16x16x32_f16(qh[m][0].v, bl0, as_[m], 0,0,0);
            ah[m]  = __builtin_amdgcn_mfma_f32_16x16x32_f16(qh[m][1].v, bh1, ah[m],  0,0,0);
        }
        #pragma unroll
        for (int m = 0; m < 4; ++m) {
            as_[m] = __builtin_amdgcn_mfma_f32_16x16x32_f16(ql[m][1].v, bh1, as_[m], 0,0,0);
            as_[m] = __builtin_amdgcn_mfma_f32_16x16x32_f16(qh[m][1].v, bl1, as_[m], 0,0,0);
        }
        int code = SUB * 16 + l15;
        float cnv = s_cn[code];
        #pragma unroll
        for (int m = 0; m < 4; ++m)
            #pragma unroll
            for (int r = 0; r < 4; ++r) {
                float d = fmaf(as_[m][r], -2.0f / LO_SCALE, fmaf(ah[m][r], -2.0f, cnv));
                ss[m][r] = fminf(ss[m][r], fmaxf(bb[m][r], d));
                ii[m][r] = (d < bb[m][r]) ? code : ii[m][r];
                bb[m][r] = fminf(bb[m][r], d);
            }
    }

    // ---- 16-lane top-2 merge; flag near-ties ----
    #pragma unroll
    for (int m = 0; m < 4; ++m)
        #pragma unroll
        for (int r = 0; r < 4; ++r) {
            float b = bb[m][r], s = ss[m][r]; int i = ii[m][r];
            #pragma unroll
            for (int mask = 1; mask < 16; mask <<= 1) {
                float ob = __shfl_xor(b, mask);
                float os = __shfl_xor(s, mask);
                int   oi = __shfl_xor(i, mask);
                float ns = fminf(fminf(s, os), fmaxf(b, ob));
                i = (ob < b || (ob == b && oi < i)) ? oi : i;
                b = fminf(b, ob);
                s = ns;
            }
            if (l15 == 0) {
                int lrow = wave * 64 + m * 16 + quad * 4 + r;
                s_bidx[lrow] = i;
                if (s - b <= DELTA) {
                    int pos = atomicAdd(&s_nflag, 1);
                    if (pos < 128) s_flist[pos] = lrow;
                }
            }
        }
    __syncthreads();

    // ---- fp64 exact refine of flagged rows (1 code/thread) ----
    int nflag = s_nflag; if (nflag > 128) nflag = 128;
    for (int fi = 0; fi < nflag; ++fi) {
        int lrow = s_flist[fi];
        int q = qb + lrow;
        if (tid < DDIM) s_q[tid] = ze[(size_t)q * DDIM + tid];
        __syncthreads();
        const float* crow = cb + (size_t)tid * DDIM;
        double a0 = 0.0, a1 = 0.0;
        #pragma unroll 8
        for (int d = 0; d < DDIM; d += 2) {
            double e0 = (double)crow[d]   - (double)s_q[d];
            double e1 = (double)crow[d+1] - (double)s_q[d+1];
            a0 = fma(e0, e0, a0);
            a1 = fma(e1, e1, a1);
        }
        double v = a0 + a1; int ki = tid;
        #pragma unroll
        for (int off = 1; off < 64; off <<= 1) {
            double ov = __shfl_xor(v, off);
            int    oi = __shfl_xor(ki, off);
            if (ov < v || (ov == v && oi < ki)) { v = ov; ki = oi; }
        }
        if (lane == 0) { s_rv[wave] = v; s_ri[wave] = ki; }
        __syncthreads();
        if (tid == 0) {
            double bv = s_rv[0]; int bk = s_ri[0];
            #pragma unroll
            for (int w = 1; w < 8; ++w)
                if (s_rv[w] < bv || (s_rv[w] == bv && s_ri[w] < bk)) { bv = s_rv[w]; bk = s_ri[w]; }
            s_bidx[lrow] = bk;
        }
        __syncthreads();
    }

    // ---- output: gather rows into reused frag LDS, dense stores ----
    {
        float4* stage = (float4*)s_mem;     // 8192 float4 = exactly 512 rows
        int bi = s_bidx[tid];
        const float4* src = (const float4*)(cb + (size_t)bi * DDIM);
        #pragma unroll
        for (int sg = 0; sg < 16; ++sg) {
            int k = (sg + tid) & 15;        // rotate: breaks 16-way bank clash
            stage[tid * 16 + k] = src[k];
        }
        __syncthreads();
        float4* dst = (float4*)(out + (size_t)qb * DDIM);
        #pragma unroll
        for (int i = 0; i < 16; ++i) dst[i * 512 + tid] = stage[i * 512 + tid];
    }
}

extern "C" void kernel_launch(void* const* d_in, const int* in_sizes, int n_in,
                              void* d_out, int out_size, void* d_ws, size_t ws_size,
                              hipStream_t stream) {
    const float* ze = (const float*)d_in[0];
    const float* cb = (const float*)d_in[1];
    float* out = (float*)d_out;

    const int nq = in_sizes[0] / DDIM;                 // 524288
    vq<<<nq / NQPB, 512, 0, stream>>>(ze, cb, out);    // 1024 blocks
}